// Round 12
// baseline (216.369 us; speedup 1.0000x reference)
//
#include <hip/hip_runtime.h>
#include <hip/hip_bf16.h>

typedef unsigned char u8;
typedef unsigned short u16;
typedef unsigned int u32;
typedef long long i64;
typedef __attribute__((ext_vector_type(8))) short bf16x8;
typedef __attribute__((ext_vector_type(4))) float f32x4;
typedef __attribute__((ext_vector_type(2))) float f32x2;

#define MAXDEG 64

// ---------- bf16 / fp8 helpers ----------
__device__ __forceinline__ u16 f2b(float f) {
    u32 u = __float_as_uint(f);
    u32 r = u + 0x7fffu + ((u >> 16) & 1u);   // round-to-nearest-even
    return (u16)(r >> 16);
}
// 4 consecutive fp8 (one u32) -> two f32x2 (HW cvt, stays packed)
__device__ __forceinline__ void load4f8v(const u8* p, f32x2& a, f32x2& b) {
    u32 q = *(const u32*)p;
    a = __builtin_amdgcn_cvt_pk_f32_fp8((int)q, false);
    b = __builtin_amdgcn_cvt_pk_f32_fp8((int)q, true);
}
__device__ __forceinline__ f32x2 vmax2(f32x2 a, f32x2 b) {
    return __builtin_elementwise_max(a, b);
}
// 8 f32 -> bf16x8 (for MFMA operand from f32 source)
__device__ __forceinline__ bf16x8 cvt8bf(const float* p) {
    float b[8];
    *(float4*)b = *(const float4*)(p);
    *(float4*)(b + 4) = *(const float4*)(p + 4);
    bf16x8 r;
#pragma unroll
    for (int j = 0; j < 8; j++) r[j] = (short)f2b(b[j]);
    return r;
}

// ---------- DPP 16-lane all-reduce-sum (VALU pipe, no LDS swizzle) ----------
// xor1 = quad_perm[1,0,3,2] (0xB1), xor2 = quad_perm[2,3,0,1] (0x4E).
// Steps 3/4 use row_half_mirror (0x141) / row_mirror (0x140): after xor1+xor2
// all lanes of a quad (resp. half-row) are equal, so the mirrored partner has
// the identical VALUE as the xor4/xor8 partner -> bit-identical sums.
template <int CTRL>
__device__ __forceinline__ float dpp_add(float x) {
    int y = __builtin_amdgcn_mov_dpp(__float_as_int(x), CTRL, 0xF, 0xF, true);
    return x + __int_as_float(y);
}
__device__ __forceinline__ float red16(float t) {
    t = dpp_add<0xB1>(t);    // + xor1
    t = dpp_add<0x4E>(t);    // + xor2
    t = dpp_add<0x141>(t);   // + cross-quad (row_half_mirror)
    t = dpp_add<0x140>(t);   // + cross-8 (row_mirror)
    return t;
}

// ---------- transposed-output GEMM tile ----------
// Computes, for this lane's row (row0+m), all 256 output channels of
// row @ W^T (+bias), fp8-quantized, written as 8 coalesced dwordx4 stores.
// MFMA operand swap: A=W fragment, B=X fragment -> D[chan][xrow];
// lane (m,quad) holds channels cth*64+quad*16+ctl*4+{0..3} of row (row0+m).
// W-row permutation per subiteration: nl = cth*64 + (m>>2)*16 + ctl*4 + (m&3)
// so a lane's 16 channels per cth are consecutive -> one dwordx4.
__device__ __forceinline__ void gemm_tile16_store(
    bf16x8 a0, bf16x8 a1, const u16* __restrict__ W,
    const float* __restrict__ bias, u8* rowOut /* table + row*256 */,
    int m, int quad) {
    int nload = ((m >> 2) << 4) + (m & 3);   // + cth*64 + ctl*4
    int cbase = quad << 4;                   // + cth*64 + ctl*4
#pragma unroll
    for (int cth = 0; cth < 4; cth++) {
        u32 pk[4];
#pragma unroll
        for (int ctl = 0; ctl < 4; ctl++) {
            int nl = cth * 64 + ctl * 4 + nload;
            bf16x8 w0 = *(const bf16x8*)(W + (size_t)nl * 64 + quad * 8);
            bf16x8 w1 = *(const bf16x8*)(W + (size_t)nl * 64 + 32 + quad * 8);
            f32x4 acc;
            if (bias) {
                float4 b4 = *(const float4*)(bias + cth * 64 + cbase + ctl * 4);
                acc[0] = b4.x; acc[1] = b4.y; acc[2] = b4.z; acc[3] = b4.w;
            } else {
                acc[0] = 0.f; acc[1] = 0.f; acc[2] = 0.f; acc[3] = 0.f;
            }
            acc = __builtin_amdgcn_mfma_f32_16x16x32_bf16(w0, a0, acc, 0, 0, 0);
            acc = __builtin_amdgcn_mfma_f32_16x16x32_bf16(w1, a1, acc, 0, 0, 0);
            u32 p = (u32)__builtin_amdgcn_cvt_pk_fp8_f32(acc[0], acc[1], 0, false);
            p = (u32)__builtin_amdgcn_cvt_pk_fp8_f32(acc[2], acc[3], (int)p, true);
            pk[ctl] = p;
        }
        uint4 v; v.x = pk[0]; v.y = pk[1]; v.z = pk[2]; v.w = pk[3];
        *(uint4*)(rowOut + cth * 64 + cbase) = v;
    }
}

// ---------- prep: small conversions + copyR + zero cnt + detect ----------
struct CJob { const float* in; void* out; int n4; int mode; };  // 0: ->bf16, 1: f32 copy
struct CJobs { CJob j[8]; };
__global__ __launch_bounds__(256) void prep_k(CJobs jobs, const u32* __restrict__ ei,
                                              int* __restrict__ flags,
                                              int* __restrict__ cnt, int N) {
    int y = blockIdx.y;
    int i = blockIdx.x * 256 + threadIdx.x;
    if (y < 8) {
        CJob job = jobs.j[y];
        if (i < job.n4) {
            float4 v = ((const float4*)job.in)[i];
            if (job.mode == 0) {
                ushort4 w;
                w.x = f2b(v.x); w.y = f2b(v.y); w.z = f2b(v.z); w.w = f2b(v.w);
                ((ushort4*)job.out)[i] = w;
            } else {
                ((float4*)job.out)[i] = v;
            }
        }
    } else {
        if (i < N) cnt[i] = 0;
        if (blockIdx.x == 0 && threadIdx.x < 64) {
            int lane = threadIdx.x;
            int oddZero = 0;
            for (int k = lane; k < 128; k += 64)
                if (ei[2 * k + 1] == 0) oddZero++;
#pragma unroll
            for (int o = 32; o > 0; o >>= 1) oddZero += __shfl_xor(oddZero, o, 64);
            if (lane == 0) flags[0] = (oddZero >= 126) ? 1 : 0;
        }
    }
}

// ---------- fused: edge bucket-build || layer-0 GEMM (+ both re tables) ----
__global__ __launch_bounds__(256) void build_gemm_k(
    const void* __restrict__ ein, const void* __restrict__ rin,
    const int* __restrict__ flags, int* __restrict__ cnt,
    int2* __restrict__ col,
    const float* __restrict__ xf, const u16* __restrict__ rel16,
    const u16* __restrict__ Wl0, const float* __restrict__ bl0,
    const u16* __restrict__ Wr0, const float* __restrict__ br0,
    const u16* __restrict__ We0, const u16* __restrict__ We1,
    u8* __restrict__ xlb, u8* __restrict__ xrb,
    u8* __restrict__ reb0, u8* __restrict__ reb1,
    int N, int E, int R, int nbBuild, int tilesN) {
    int b = blockIdx.x;
    if (b < nbBuild) {
        int i = b * 256 + threadIdx.x;
        if (i < E) {
            int f = flags[0];
            int s, d, r;
            if (f) {
                s = (int)((const i64*)ein)[i];
                d = (int)((const i64*)ein)[E + i];
                r = (int)((const i64*)rin)[i];
            } else {
                s = ((const int*)ein)[i];
                d = ((const int*)ein)[E + i];
                r = ((const int*)rin)[i];
            }
            s = max(0, min(s, N - 1));
            d = max(0, min(d, N - 1));
            r = max(0, min(r, R - 1));
            int slot = atomicAdd(&cnt[d], 1);
            if (slot < MAXDEG)
                col[(d << 6) + slot] = make_int2(s << 8, r << 8);  // pre-scaled
        }
        return;
    }
    int g = b - nbBuild;
    int wave = threadIdx.x >> 6, lane = threadIdx.x & 63;
    int m = lane & 15, quad = lane >> 4;

    const u16* WA;
    const u16* WB = nullptr;        // dual output if non-null
    const float* biasA = nullptr;
    const float* biasB = nullptr;
    u8* outA;
    u8* outB = nullptr;
    int rows, row0;
    bf16x8 a0, a1;
    if (g < tilesN) {
        rows = N; row0 = g * 64 + wave * 16;
        if (row0 >= rows) return;
        WA = Wl0; biasA = bl0; outA = xlb;
        WB = Wr0; biasB = br0; outB = xrb;
        size_t row = (size_t)row0 + m;
        a0 = cvt8bf(xf + row * 64 + quad * 8);
        a1 = cvt8bf(xf + row * 64 + 32 + quad * 8);
    } else {
        int g2 = g - tilesN;        // 0..15
        int layer = g2 >> 3;
        rows = R; row0 = (g2 & 7) * 64 + wave * 16;
        if (row0 >= rows) return;
        WA = layer ? We1 : We0;
        outA = layer ? reb1 : reb0;
        size_t row = (size_t)row0 + m;
        a0 = *(const bf16x8*)(rel16 + row * 64 + quad * 8);
        a1 = *(const bf16x8*)(rel16 + row * 64 + 32 + quad * 8);
    }

    u8* rowA = outA + (size_t)(row0 + m) * 256;
    gemm_tile16_store(a0, a1, WA, biasA, rowA, m, quad);
    if (WB) {
        u8* rowB = outB + (size_t)(row0 + m) * 256;
        gemm_tile16_store(a0, a1, WB, biasB, rowB, m, quad);
    }
}

// ---------- layer-1 GEMM (N rows): h0(bf16) @ {Wl1,Wr1} -> xlb,xrb ----------
__global__ __launch_bounds__(256) void gemm_n_k(
    const u16* __restrict__ Xin,
    const u16* __restrict__ Wl16, const float* __restrict__ bl,
    const u16* __restrict__ Wr16, const float* __restrict__ br,
    u8* __restrict__ xl, u8* __restrict__ xr, int N) {
    int wave = threadIdx.x >> 6, lane = threadIdx.x & 63;
    int row0 = blockIdx.x * 64 + wave * 16;
    if (row0 >= N) return;
    int m = lane & 15, quad = lane >> 4;
    size_t row = (size_t)row0 + m;
    bf16x8 a0 = *(const bf16x8*)(Xin + row * 64 + quad * 8);
    bf16x8 a1 = *(const bf16x8*)(Xin + row * 64 + 32 + quad * 8);

    gemm_tile16_store(a0, a1, Wl16, bl, xl + row * 256, m, quad);
    gemm_tile16_store(a0, a1, Wr16, br, xr + row * 256, m, quad);
}

// ---------- fused edge phase: 2 waves per node (split-K over edges) --------
// lane: head h = lane>>4, channels ci..ci+3, ci = (lane&15)*4. Fixed-ref
// softmax, packed f32 math, DPP alpha-reduce (r6), r6 direct cb[e] loads
// (ping-pong r7/r9 were neutral -> wave-level ILP exhausted; this doubles
// TLP instead). Block = 256 thr = 2 nodes x 2 waves. Wave half 0 takes
// groups [0,G/2), half 1 takes [G/2,G) + remainder; partials combine via
// LDS + one barrier; half 0 adds self-loop (needs combined mea) + stores.
// No early return before the barrier (invalid nodes clamp, store masked).
__global__ __launch_bounds__(256) void edge_agg(
    const int* __restrict__ cnt, const int2* __restrict__ col,
    const u8* __restrict__ xl, const u8* __restrict__ xr,
    const u8* __restrict__ re,
    const float* __restrict__ att, const float* __restrict__ bias,
    u16* __restrict__ outB, float* __restrict__ outF, int writeF32, int N) {
    int wid = threadIdx.x >> 6;
    int lane = threadIdx.x & 63;
    int nodeSlot = wid >> 1;     // 0,1: which node of this block
    int half = wid & 1;          // 0,1: which edge-half of that node
    int node = blockIdx.x * 2 + nodeSlot;
    int valid = node < N;
    int nodeC = __builtin_amdgcn_readfirstlane(valid ? node : N - 1);

    int h = lane >> 4;
    int ci = (lane & 15) * 4;
    u32 hoff = (u32)(h * 64 + ci);
    const u8* xlh = xl + hoff;     // per-lane table bases (col idx pre-scaled)
    const u8* xrh = xr + hoff;
    const u8* reh = re + hoff;

    f32x2 avA, avB;
    {
        float4 a4 = *(const float4*)(att + hoff);
        avA[0] = a4.x; avA[1] = a4.y; avB[0] = a4.z; avB[1] = a4.w;
    }
    f32x2 xlA, xlB, xrA, xrB;
    load4f8v(xlh + ((u32)nodeC << 8), xlA, xlB);
    load4f8v(xrh + ((u32)nodeC << 8), xrA, xrB);

    int degc = __builtin_amdgcn_readfirstlane(cnt[nodeC]);
    int deg = min(degc, MAXDEG);
    const int2* cb = col + ((u32)nodeC << 6);

    float l = 0.f;
    f32x2 accA = {0.f, 0.f}, accB = {0.f, 0.f};
    f32x2 meaA = {0.f, 0.f}, meaB = {0.f, 0.f};

#define EDGE_MATH(xA, xB, vA, vB, tout)                \
    {                                                  \
        f32x2 mA = (xA + xrA) + vA;                    \
        f32x2 mB = (xB + xrB) + vB;                    \
        mA = vmax2(mA, mA * 0.2f);                     \
        mB = vmax2(mB, mB * 0.2f);                     \
        f32x2 tt = avA * mA + avB * mB;                \
        meaA += vA; meaB += vB;                        \
        tout = tt[0] + tt[1];                          \
    }

    int G = deg >> 2;                  // full 4-edge groups
    int gBeg = half ? (G >> 1) : 0;
    int gEnd = half ? G : (G >> 1);
    for (int g = gBeg; g < gEnd; ++g) {
        int e = g * 4;
        int2 c0 = cb[e], c1 = cb[e + 1], c2 = cb[e + 2], c3 = cb[e + 3];
        f32x2 x0A, x0B, x1A, x1B, x2A, x2B, x3A, x3B;
        f32x2 v0A, v0B, v1A, v1B, v2A, v2B, v3A, v3B;
        load4f8v(xlh + (u32)c0.x, x0A, x0B);
        load4f8v(xlh + (u32)c1.x, x1A, x1B);
        load4f8v(xlh + (u32)c2.x, x2A, x2B);
        load4f8v(xlh + (u32)c3.x, x3A, x3B);
        load4f8v(reh + (u32)c0.y, v0A, v0B);
        load4f8v(reh + (u32)c1.y, v1A, v1B);
        load4f8v(reh + (u32)c2.y, v2A, v2B);
        load4f8v(reh + (u32)c3.y, v3A, v3B);
        float t0, t1, t2, t3;
        EDGE_MATH(x0A, x0B, v0A, v0B, t0);
        EDGE_MATH(x1A, x1B, v1A, v1B, t1);
        EDGE_MATH(x2A, x2B, v2A, v2B, t2);
        EDGE_MATH(x3A, x3B, v3A, v3B, t3);
        t0 = red16(t0);
        t1 = red16(t1);
        t2 = red16(t2);
        t3 = red16(t3);
        float p0 = __expf(t0), p1 = __expf(t1);
        float p2 = __expf(t2), p3 = __expf(t3);
        l += (p0 + p1) + (p2 + p3);
        accA += (x0A * p0 + x1A * p1) + (x2A * p2 + x3A * p3);
        accB += (x0B * p0 + x1B * p1) + (x2B * p2 + x3B * p3);
    }
    if (half) {
        for (int e = G * 4; e < deg; ++e) {
            int2 c0 = cb[e];
            f32x2 x0A, x0B, v0A, v0B;
            load4f8v(xlh + (u32)c0.x, x0A, x0B);
            load4f8v(reh + (u32)c0.y, v0A, v0B);
            float t0;
            EDGE_MATH(x0A, x0B, v0A, v0B, t0);
            t0 = red16(t0);
            float p0 = __expf(t0);
            l += p0;
            accA += x0A * p0;
            accB += x0B * p0;
        }
    }
#undef EDGE_MATH

    // ---- combine the two halves through LDS (stride 9 -> conflict-free) ----
    __shared__ float part[2][64][9];
    if (half) {
        float* p = part[nodeSlot][lane];
        p[0] = accA[0]; p[1] = accA[1]; p[2] = accB[0]; p[3] = accB[1];
        p[4] = meaA[0]; p[5] = meaA[1]; p[6] = meaB[0]; p[7] = meaB[1];
        p[8] = l;
    }
    __syncthreads();
    if (half) return;

    {
        const float* p = part[nodeSlot][lane];
        accA[0] += p[0]; accA[1] += p[1]; accB[0] += p[2]; accB[1] += p[3];
        meaA[0] += p[4]; meaA[1] += p[5]; meaB[0] += p[6]; meaB[1] += p[7];
        l += p[8];
    }

    // self-loop LAST: m = xl[n] + xr[n] + mean(incoming re rows)
    {
        float inv_d = 1.0f / fmaxf((float)degc, 1.0f);
        f32x2 mA = (xlA + xrA) + meaA * inv_d;
        f32x2 mB = (xlB + xrB) + meaB * inv_d;
        mA = vmax2(mA, mA * 0.2f);
        mB = vmax2(mB, mB * 0.2f);
        f32x2 tt = avA * mA + avB * mB;
        float ts = tt[0] + tt[1];
        ts = red16(ts);
        float ps = __expf(ts);
        l += ps;
        accA += xlA * ps;
        accB += xlB * ps;
    }

    float invl = 1.0f / l;
    float o0 = accA[0] * invl, o1 = accA[1] * invl;
    float o2 = accB[0] * invl, o3 = accB[1] * invl;
    // sum across the 4 head groups (lanes differing in bits 4,5)
    o0 += __shfl_xor(o0, 16, 64); o0 += __shfl_xor(o0, 32, 64);
    o1 += __shfl_xor(o1, 16, 64); o1 += __shfl_xor(o1, 32, 64);
    o2 += __shfl_xor(o2, 16, 64); o2 += __shfl_xor(o2, 32, 64);
    o3 += __shfl_xor(o3, 16, 64); o3 += __shfl_xor(o3, 32, 64);
    if (lane < 16 && valid) {
        float4 b4 = *(const float4*)(bias + ci);
        float r0 = o0 * 0.25f + b4.x;
        float r1 = o1 * 0.25f + b4.y;
        float r2 = o2 * 0.25f + b4.z;
        float r3 = o3 * 0.25f + b4.w;
        if (writeF32) {
            float4 w = {r0, r1, r2, r3};
            *(float4*)(outF + (size_t)node * 64 + ci) = w;
        } else {
            ushort4 w;
            w.x = f2b(r0); w.y = f2b(r1); w.z = f2b(r2); w.w = f2b(r3);
            *(ushort4*)(outB + (size_t)node * 64 + ci) = w;
        }
    }
}

// ---------- launch ----------
extern "C" void kernel_launch(void* const* d_in, const int* in_sizes, int n_in,
                              void* d_out, int out_size, void* d_ws, size_t ws_size,
                              hipStream_t stream) {
    const float* xf   = (const float*)d_in[0];
    const float* relf = (const float*)d_in[2];

    const int N = in_sizes[0] / 64;   // 20000
    const int E = in_sizes[3];        // 320000
    const int R = in_sizes[2] / 64;   // 512

    const float* Wl[2] = {(const float*)d_in[4],  (const float*)d_in[11]};
    const float* bl[2] = {(const float*)d_in[5],  (const float*)d_in[12]};
    const float* Wr[2] = {(const float*)d_in[6],  (const float*)d_in[13]};
    const float* br[2] = {(const float*)d_in[7],  (const float*)d_in[14]};
    const float* We[2] = {(const float*)d_in[8],  (const float*)d_in[15]};
    const float* at[2] = {(const float*)d_in[9],  (const float*)d_in[16]};
    const float* bb[2] = {(const float*)d_in[10], (const float*)d_in[17]};

    // workspace carve
    char* p = (char*)d_ws;
    auto alloc = [&](size_t bytes) -> void* {
        void* r = (void*)p;
        p += (bytes + 255) & ~(size_t)255;
        return r;
    };
    int* flags   = (int*)alloc(256);
    u16* rel16   = (u16*)alloc((size_t)R * 64 * 2);
    u16* w16[6];
    for (int i = 0; i < 6; i++) w16[i] = (u16*)alloc((size_t)256 * 64 * 2);
    int* cnt     = (int*)alloc((size_t)N * 4);
    int2* col    = (int2*)alloc((size_t)N * MAXDEG * 8);
    u8* xlb  = (u8*)alloc((size_t)N * 256);
    u8* xrb  = (u8*)alloc((size_t)N * 256);
    u8* reb0 = (u8*)alloc((size_t)R * 256);
    u8* reb1 = (u8*)alloc((size_t)R * 256);
    u16* h0  = (u16*)alloc((size_t)N * 64 * 2);

    float* out = (float*)d_out;

    // 1. prep: small conversions (+copyR), zero cnt, detect index storage
    CJobs jobs;
    jobs.j[0] = {relf,  rel16,  R * 16,   0};
    jobs.j[1] = {Wl[0], w16[0], 256 * 16, 0};
    jobs.j[2] = {Wr[0], w16[1], 256 * 16, 0};
    jobs.j[3] = {We[0], w16[2], 256 * 16, 0};
    jobs.j[4] = {Wl[1], w16[3], 256 * 16, 0};
    jobs.j[5] = {Wr[1], w16[4], 256 * 16, 0};
    jobs.j[6] = {We[1], w16[5], 256 * 16, 0};
    jobs.j[7] = {relf,  out + (size_t)N * 64, R * 16, 1};
    dim3 pgrid((N + 255) / 256, 9);
    prep_k<<<pgrid, 256, 0, stream>>>(jobs, (const u32*)d_in[1], flags, cnt, N);

    // 2. edge bucket-build || layer-0 GEMM (+ re tables for both layers)
    const int nbBuild = (E + 255) / 256;
    const int tilesN = (N + 63) / 64;
    build_gemm_k<<<nbBuild + tilesN + 16, 256, 0, stream>>>(
        d_in[1], d_in[3], flags, cnt, col, xf, rel16,
        w16[0], bl[0], w16[1], br[0], w16[2], w16[5],
        xlb, xrb, reb0, reb1, N, E, R, nbBuild, tilesN);

    // 3. layer-0 edge phase -> h0 (bf16); 2 nodes per block
    edge_agg<<<(N + 1) / 2, 256, 0, stream>>>(cnt, col, xlb, xrb, reb0,
                                              at[0], bb[0], h0, out, 0, N);

    // 4. layer-1 GEMM (N rows): h0 @ {Wl1,Wr1}
    gemm_n_k<<<tilesN, 256, 0, stream>>>(h0, w16[3], bl[1], w16[4], br[1],
                                         xlb, xrb, N);

    // 5. layer-1 edge phase -> out (f32)
    edge_agg<<<(N + 1) / 2, 256, 0, stream>>>(cnt, col, xlb, xrb, reb1,
                                              at[1], bb[1], h0, out, 1, N);
}

// Round 17
// 211.808 us; speedup vs baseline: 1.0215x; 1.0215x over previous
//
#include <hip/hip_runtime.h>
#include <hip/hip_bf16.h>

typedef unsigned char u8;
typedef unsigned short u16;
typedef unsigned int u32;
typedef long long i64;
typedef __attribute__((ext_vector_type(8))) short bf16x8;
typedef __attribute__((ext_vector_type(4))) float f32x4;
typedef __attribute__((ext_vector_type(2))) float f32x2;

#define MAXDEG 64

// ---------- bf16 / fp8 helpers ----------
__device__ __forceinline__ u16 f2b(float f) {
    u32 u = __float_as_uint(f);
    u32 r = u + 0x7fffu + ((u >> 16) & 1u);   // round-to-nearest-even
    return (u16)(r >> 16);
}
// raw u32 of 4 fp8 -> two f32x2 (HW cvt, stays packed)
__device__ __forceinline__ void dec4f8(u32 q, f32x2& a, f32x2& b) {
    a = __builtin_amdgcn_cvt_pk_f32_fp8((int)q, false);
    b = __builtin_amdgcn_cvt_pk_f32_fp8((int)q, true);
}
__device__ __forceinline__ void load4f8v(const u8* p, f32x2& a, f32x2& b) {
    dec4f8(*(const u32*)p, a, b);
}
__device__ __forceinline__ f32x2 vmax2(f32x2 a, f32x2 b) {
    return __builtin_elementwise_max(a, b);
}
// 8 f32 -> bf16x8 (for MFMA operand from f32 source)
__device__ __forceinline__ bf16x8 cvt8bf(const float* p) {
    float b[8];
    *(float4*)b = *(const float4*)(p);
    *(float4*)(b + 4) = *(const float4*)(p + 4);
    bf16x8 r;
#pragma unroll
    for (int j = 0; j < 8; j++) r[j] = (short)f2b(b[j]);
    return r;
}

// ---------- DPP 16-lane all-reduce-sum (VALU pipe, no LDS swizzle) ----------
// xor1 = quad_perm[1,0,3,2] (0xB1), xor2 = quad_perm[2,3,0,1] (0x4E).
// Steps 3/4 use row_half_mirror (0x141) / row_mirror (0x140): after xor1+xor2
// all lanes of a quad (resp. half-row) are equal, so the mirrored partner has
// the identical VALUE as the xor4/xor8 partner -> bit-identical sums.
template <int CTRL>
__device__ __forceinline__ float dpp_add(float x) {
    int y = __builtin_amdgcn_mov_dpp(__float_as_int(x), CTRL, 0xF, 0xF, true);
    return x + __int_as_float(y);
}
__device__ __forceinline__ float red16(float t) {
    t = dpp_add<0xB1>(t);    // + xor1
    t = dpp_add<0x4E>(t);    // + xor2
    t = dpp_add<0x141>(t);   // + cross-quad (row_half_mirror)
    t = dpp_add<0x140>(t);   // + cross-8 (row_mirror)
    return t;
}

// ---------- transposed-output GEMM tile ----------
// Computes, for this lane's row (row0+m), all 256 output channels of
// row @ W^T (+bias), fp8-quantized, written as 8 coalesced dwordx4 stores.
// MFMA operand swap: A=W fragment, B=X fragment -> D[chan][xrow];
// lane (m,quad) holds channels cth*64+quad*16+ctl*4+{0..3} of row (row0+m).
// W-row permutation per subiteration: nl = cth*64 + (m>>2)*16 + ctl*4 + (m&3)
// so a lane's 16 channels per cth are consecutive -> one dwordx4.
__device__ __forceinline__ void gemm_tile16_store(
    bf16x8 a0, bf16x8 a1, const u16* __restrict__ W,
    const float* __restrict__ bias, u8* rowOut /* table + row*256 */,
    int m, int quad) {
    int nload = ((m >> 2) << 4) + (m & 3);   // + cth*64 + ctl*4
    int cbase = quad << 4;                   // + cth*64 + ctl*4
#pragma unroll
    for (int cth = 0; cth < 4; cth++) {
        u32 pk[4];
#pragma unroll
        for (int ctl = 0; ctl < 4; ctl++) {
            int nl = cth * 64 + ctl * 4 + nload;
            bf16x8 w0 = *(const bf16x8*)(W + (size_t)nl * 64 + quad * 8);
            bf16x8 w1 = *(const bf16x8*)(W + (size_t)nl * 64 + 32 + quad * 8);
            f32x4 acc;
            if (bias) {
                float4 b4 = *(const float4*)(bias + cth * 64 + cbase + ctl * 4);
                acc[0] = b4.x; acc[1] = b4.y; acc[2] = b4.z; acc[3] = b4.w;
            } else {
                acc[0] = 0.f; acc[1] = 0.f; acc[2] = 0.f; acc[3] = 0.f;
            }
            acc = __builtin_amdgcn_mfma_f32_16x16x32_bf16(w0, a0, acc, 0, 0, 0);
            acc = __builtin_amdgcn_mfma_f32_16x16x32_bf16(w1, a1, acc, 0, 0, 0);
            u32 p = (u32)__builtin_amdgcn_cvt_pk_fp8_f32(acc[0], acc[1], 0, false);
            p = (u32)__builtin_amdgcn_cvt_pk_fp8_f32(acc[2], acc[3], (int)p, true);
            pk[ctl] = p;
        }
        uint4 v; v.x = pk[0]; v.y = pk[1]; v.z = pk[2]; v.w = pk[3];
        *(uint4*)(rowOut + cth * 64 + cbase) = v;
    }
}

// ---------- prep: small conversions + copyR + zero cnt + detect ----------
struct CJob { const float* in; void* out; int n4; int mode; };  // 0: ->bf16, 1: f32 copy
struct CJobs { CJob j[8]; };
__global__ __launch_bounds__(256) void prep_k(CJobs jobs, const u32* __restrict__ ei,
                                              int* __restrict__ flags,
                                              int* __restrict__ cnt, int N) {
    int y = blockIdx.y;
    int i = blockIdx.x * 256 + threadIdx.x;
    if (y < 8) {
        CJob job = jobs.j[y];
        if (i < job.n4) {
            float4 v = ((const float4*)job.in)[i];
            if (job.mode == 0) {
                ushort4 w;
                w.x = f2b(v.x); w.y = f2b(v.y); w.z = f2b(v.z); w.w = f2b(v.w);
                ((ushort4*)job.out)[i] = w;
            } else {
                ((float4*)job.out)[i] = v;
            }
        }
    } else {
        if (i < N) cnt[i] = 0;
        if (blockIdx.x == 0 && threadIdx.x < 64) {
            int lane = threadIdx.x;
            int oddZero = 0;
            for (int k = lane; k < 128; k += 64)
                if (ei[2 * k + 1] == 0) oddZero++;
#pragma unroll
            for (int o = 32; o > 0; o >>= 1) oddZero += __shfl_xor(oddZero, o, 64);
            if (lane == 0) flags[0] = (oddZero >= 126) ? 1 : 0;
        }
    }
}

// ---------- fused: edge bucket-build || layer-0 GEMM (+ both re tables) ----
__global__ __launch_bounds__(256) void build_gemm_k(
    const void* __restrict__ ein, const void* __restrict__ rin,
    const int* __restrict__ flags, int* __restrict__ cnt,
    int2* __restrict__ col,
    const float* __restrict__ xf, const u16* __restrict__ rel16,
    const u16* __restrict__ Wl0, const float* __restrict__ bl0,
    const u16* __restrict__ Wr0, const float* __restrict__ br0,
    const u16* __restrict__ We0, const u16* __restrict__ We1,
    u8* __restrict__ xlb, u8* __restrict__ xrb,
    u8* __restrict__ reb0, u8* __restrict__ reb1,
    int N, int E, int R, int nbBuild, int tilesN) {
    int b = blockIdx.x;
    if (b < nbBuild) {
        int i = b * 256 + threadIdx.x;
        if (i < E) {
            int f = flags[0];
            int s, d, r;
            if (f) {
                s = (int)((const i64*)ein)[i];
                d = (int)((const i64*)ein)[E + i];
                r = (int)((const i64*)rin)[i];
            } else {
                s = ((const int*)ein)[i];
                d = ((const int*)ein)[E + i];
                r = ((const int*)rin)[i];
            }
            s = max(0, min(s, N - 1));
            d = max(0, min(d, N - 1));
            r = max(0, min(r, R - 1));
            int slot = atomicAdd(&cnt[d], 1);
            if (slot < MAXDEG)
                col[(d << 6) + slot] = make_int2(s << 8, r << 8);  // pre-scaled
        }
        return;
    }
    int g = b - nbBuild;
    int wave = threadIdx.x >> 6, lane = threadIdx.x & 63;
    int m = lane & 15, quad = lane >> 4;

    const u16* WA;
    const u16* WB = nullptr;        // dual output if non-null
    const float* biasA = nullptr;
    const float* biasB = nullptr;
    u8* outA;
    u8* outB = nullptr;
    int rows, row0;
    bf16x8 a0, a1;
    if (g < tilesN) {
        rows = N; row0 = g * 64 + wave * 16;
        if (row0 >= rows) return;
        WA = Wl0; biasA = bl0; outA = xlb;
        WB = Wr0; biasB = br0; outB = xrb;
        size_t row = (size_t)row0 + m;
        a0 = cvt8bf(xf + row * 64 + quad * 8);
        a1 = cvt8bf(xf + row * 64 + 32 + quad * 8);
    } else {
        int g2 = g - tilesN;        // 0..15
        int layer = g2 >> 3;
        rows = R; row0 = (g2 & 7) * 64 + wave * 16;
        if (row0 >= rows) return;
        WA = layer ? We1 : We0;
        outA = layer ? reb1 : reb0;
        size_t row = (size_t)row0 + m;
        a0 = *(const bf16x8*)(rel16 + row * 64 + quad * 8);
        a1 = *(const bf16x8*)(rel16 + row * 64 + 32 + quad * 8);
    }

    u8* rowA = outA + (size_t)(row0 + m) * 256;
    gemm_tile16_store(a0, a1, WA, biasA, rowA, m, quad);
    if (WB) {
        u8* rowB = outB + (size_t)(row0 + m) * 256;
        gemm_tile16_store(a0, a1, WB, biasB, rowB, m, quad);
    }
}

// ---------- layer-1 GEMM (N rows): h0(bf16) @ {Wl1,Wr1} -> xlb,xrb ----------
__global__ __launch_bounds__(256) void gemm_n_k(
    const u16* __restrict__ Xin,
    const u16* __restrict__ Wl16, const float* __restrict__ bl,
    const u16* __restrict__ Wr16, const float* __restrict__ br,
    u8* __restrict__ xl, u8* __restrict__ xr, int N) {
    int wave = threadIdx.x >> 6, lane = threadIdx.x & 63;
    int row0 = blockIdx.x * 64 + wave * 16;
    if (row0 >= N) return;
    int m = lane & 15, quad = lane >> 4;
    size_t row = (size_t)row0 + m;
    bf16x8 a0 = *(const bf16x8*)(Xin + row * 64 + quad * 8);
    bf16x8 a1 = *(const bf16x8*)(Xin + row * 64 + 32 + quad * 8);

    gemm_tile16_store(a0, a1, Wl16, bl, xl + row * 256, m, quad);
    gemm_tile16_store(a0, a1, Wr16, br, xr + row * 256, m, quad);
}

// ---------- fused edge phase: ONE wave owns TWO nodes (cross-node ILP) -----
// lane: head h = lane>>4, channels ci..ci+3, ci = (lane&15)*4. Fixed-ref
// softmax, packed f32 math, DPP alpha-reduce (r6 structure, 207.6us best).
// r7/r9 in-node ping-pong: neutral (chain through shared acc). r12 split-K
// 2-waves/node: -4% (duplicated fixed overhead). This round: interleave TWO
// INDEPENDENT nodes' edge-group streams in one wave — node1's cb+gathers
// issue while node0's decode/math/exp runs; zero extra barriers/overhead;
// per-node FP order unchanged (bit-identical absmax). Guards g<G0/G1 are
// wave-uniform (deg readfirstlane'd) -> scalar branches.
// (r16 fix: macro-internal int2 names _lc0.._lc3 to avoid shadowing callers.)
__global__ __launch_bounds__(256) void edge_agg(
    const int* __restrict__ cnt, const int2* __restrict__ col,
    const u8* __restrict__ xl, const u8* __restrict__ xr,
    const u8* __restrict__ re,
    const float* __restrict__ att, const float* __restrict__ bias,
    u16* __restrict__ outB, float* __restrict__ outF, int writeF32, int N) {
    int wid = threadIdx.x >> 6;
    int lane = threadIdx.x & 63;
    int base = (blockIdx.x * 4 + wid) * 2;
    if (base >= N) return;
    int v0 = base < N, v1 = base + 1 < N;
    int n0 = __builtin_amdgcn_readfirstlane(min(base, N - 1));
    int n1 = __builtin_amdgcn_readfirstlane(min(base + 1, N - 1));

    int h = lane >> 4;
    int ci = (lane & 15) * 4;
    u32 hoff = (u32)(h * 64 + ci);
    const u8* xlh = xl + hoff;     // per-lane table bases (col idx pre-scaled)
    const u8* xrh = xr + hoff;
    const u8* reh = re + hoff;

    f32x2 avA, avB;
    {
        float4 a4 = *(const float4*)(att + hoff);
        avA[0] = a4.x; avA[1] = a4.y; avB[0] = a4.z; avB[1] = a4.w;
    }
    f32x2 xlA0, xlB0, xrA0, xrB0, xlA1, xlB1, xrA1, xrB1;
    load4f8v(xlh + ((u32)n0 << 8), xlA0, xlB0);
    load4f8v(xrh + ((u32)n0 << 8), xrA0, xrB0);
    load4f8v(xlh + ((u32)n1 << 8), xlA1, xlB1);
    load4f8v(xrh + ((u32)n1 << 8), xrA1, xrB1);

    int degc0 = __builtin_amdgcn_readfirstlane(cnt[n0]);
    int degc1 = __builtin_amdgcn_readfirstlane(cnt[n1]);
    int deg0 = min(degc0, MAXDEG), deg1 = min(degc1, MAXDEG);
    const int2* cb0 = col + ((u32)n0 << 6);
    const int2* cb1 = col + ((u32)n1 << 6);

    float l0 = 0.f, l1 = 0.f;
    f32x2 accA0 = {0.f, 0.f}, accB0 = {0.f, 0.f};
    f32x2 meaA0 = {0.f, 0.f}, meaB0 = {0.f, 0.f};
    f32x2 accA1 = {0.f, 0.f}, accB1 = {0.f, 0.f};
    f32x2 meaA1 = {0.f, 0.f}, meaB1 = {0.f, 0.f};

#define EDGE_MATH(xA, xB, vA, vB, xrA_, xrB_, meaA_, meaB_, tout)   \
    {                                                               \
        f32x2 mA = (xA + xrA_) + vA;                                \
        f32x2 mB = (xB + xrB_) + vB;                                \
        mA = vmax2(mA, mA * 0.2f);                                  \
        mB = vmax2(mB, mB * 0.2f);                                  \
        f32x2 tt = avA * mA + avB * mB;                             \
        meaA_ += vA; meaB_ += vB;                                   \
        tout = tt[0] + tt[1];                                       \
    }

#define LOADG(cbp, e0, X0, X1, X2, X3, R0, R1, R2, R3)              \
    {                                                               \
        int2 _lc0 = cbp[(e0) + 0], _lc1 = cbp[(e0) + 1];            \
        int2 _lc2 = cbp[(e0) + 2], _lc3 = cbp[(e0) + 3];            \
        X0 = *(const u32*)(xlh + (u32)_lc0.x);                      \
        X1 = *(const u32*)(xlh + (u32)_lc1.x);                      \
        X2 = *(const u32*)(xlh + (u32)_lc2.x);                      \
        X3 = *(const u32*)(xlh + (u32)_lc3.x);                      \
        R0 = *(const u32*)(reh + (u32)_lc0.y);                      \
        R1 = *(const u32*)(reh + (u32)_lc1.y);                      \
        R2 = *(const u32*)(reh + (u32)_lc2.y);                      \
        R3 = *(const u32*)(reh + (u32)_lc3.y);                      \
    }

#define COMPUTE4(X0, X1, X2, X3, R0, R1, R2, R3, xrA_, xrB_, l_,    \
                 accA_, accB_, meaA_, meaB_)                        \
    {                                                               \
        f32x2 x0A, x0B, x1A, x1B, x2A, x2B, x3A, x3B;               \
        f32x2 v0A, v0B, v1A, v1B, v2A, v2B, v3A, v3B;               \
        dec4f8(X0, x0A, x0B); dec4f8(X1, x1A, x1B);                 \
        dec4f8(X2, x2A, x2B); dec4f8(X3, x3A, x3B);                 \
        dec4f8(R0, v0A, v0B); dec4f8(R1, v1A, v1B);                 \
        dec4f8(R2, v2A, v2B); dec4f8(R3, v3A, v3B);                 \
        float t0, t1, t2, t3;                                       \
        EDGE_MATH(x0A, x0B, v0A, v0B, xrA_, xrB_, meaA_, meaB_, t0);\
        EDGE_MATH(x1A, x1B, v1A, v1B, xrA_, xrB_, meaA_, meaB_, t1);\
        EDGE_MATH(x2A, x2B, v2A, v2B, xrA_, xrB_, meaA_, meaB_, t2);\
        EDGE_MATH(x3A, x3B, v3A, v3B, xrA_, xrB_, meaA_, meaB_, t3);\
        t0 = red16(t0); t1 = red16(t1);                             \
        t2 = red16(t2); t3 = red16(t3);                             \
        float p0 = __expf(t0), p1 = __expf(t1);                     \
        float p2 = __expf(t2), p3 = __expf(t3);                     \
        l_ += (p0 + p1) + (p2 + p3);                                \
        accA_ += (x0A * p0 + x1A * p1) + (x2A * p2 + x3A * p3);     \
        accB_ += (x0B * p0 + x1B * p1) + (x2B * p2 + x3B * p3);     \
    }

    int G0 = deg0 >> 2, G1 = deg1 >> 2;
    int Gm = max(G0, G1);
    for (int g = 0; g < Gm; ++g) {
        u32 qa0, qa1, qa2, qa3, qb0, qb1, qb2, qb3;
        u32 qc0, qc1, qc2, qc3, qd0, qd1, qd2, qd3;
        if (g < G0) LOADG(cb0, g * 4, qa0, qa1, qa2, qa3, qb0, qb1, qb2, qb3);
        if (g < G1) LOADG(cb1, g * 4, qc0, qc1, qc2, qc3, qd0, qd1, qd2, qd3);
        if (g < G0) COMPUTE4(qa0, qa1, qa2, qa3, qb0, qb1, qb2, qb3,
                             xrA0, xrB0, l0, accA0, accB0, meaA0, meaB0);
        if (g < G1) COMPUTE4(qc0, qc1, qc2, qc3, qd0, qd1, qd2, qd3,
                             xrA1, xrB1, l1, accA1, accB1, meaA1, meaB1);
    }
    for (int e = G0 * 4; e < deg0; ++e) {
        int2 c = cb0[e];
        f32x2 x0A, x0B, v0A, v0B;
        load4f8v(xlh + (u32)c.x, x0A, x0B);
        load4f8v(reh + (u32)c.y, v0A, v0B);
        float t0;
        EDGE_MATH(x0A, x0B, v0A, v0B, xrA0, xrB0, meaA0, meaB0, t0);
        t0 = red16(t0);
        float p0 = __expf(t0);
        l0 += p0; accA0 += x0A * p0; accB0 += x0B * p0;
    }
    for (int e = G1 * 4; e < deg1; ++e) {
        int2 c = cb1[e];
        f32x2 x0A, x0B, v0A, v0B;
        load4f8v(xlh + (u32)c.x, x0A, x0B);
        load4f8v(reh + (u32)c.y, v0A, v0B);
        float t0;
        EDGE_MATH(x0A, x0B, v0A, v0B, xrA1, xrB1, meaA1, meaB1, t0);
        t0 = red16(t0);
        float p0 = __expf(t0);
        l1 += p0; accA1 += x0A * p0; accB1 += x0B * p0;
    }
#undef COMPUTE4
#undef LOADG

// self-loop LAST (m = xl+xr+mean(re)), then head-mean + bias + store
#define FINISH(node_, valid_, degc_, xlA_, xlB_, xrA_, xrB_, l_,    \
               accA_, accB_, meaA_, meaB_)                          \
    {                                                               \
        float inv_d = 1.0f / fmaxf((float)degc_, 1.0f);             \
        f32x2 mA = (xlA_ + xrA_) + meaA_ * inv_d;                   \
        f32x2 mB = (xlB_ + xrB_) + meaB_ * inv_d;                   \
        mA = vmax2(mA, mA * 0.2f);                                  \
        mB = vmax2(mB, mB * 0.2f);                                  \
        f32x2 tt = avA * mA + avB * mB;                             \
        float ts = tt[0] + tt[1];                                   \
        ts = red16(ts);                                             \
        float ps = __expf(ts);                                      \
        l_ += ps;                                                   \
        accA_ += xlA_ * ps;                                         \
        accB_ += xlB_ * ps;                                         \
        float invl = 1.0f / l_;                                     \
        float o0 = accA_[0] * invl, o1 = accA_[1] * invl;           \
        float o2 = accB_[0] * invl, o3 = accB_[1] * invl;           \
        o0 += __shfl_xor(o0, 16, 64); o0 += __shfl_xor(o0, 32, 64); \
        o1 += __shfl_xor(o1, 16, 64); o1 += __shfl_xor(o1, 32, 64); \
        o2 += __shfl_xor(o2, 16, 64); o2 += __shfl_xor(o2, 32, 64); \
        o3 += __shfl_xor(o3, 16, 64); o3 += __shfl_xor(o3, 32, 64); \
        if (lane < 16 && valid_) {                                  \
            float4 b4 = *(const float4*)(bias + ci);                \
            float r0 = o0 * 0.25f + b4.x;                           \
            float r1 = o1 * 0.25f + b4.y;                           \
            float r2 = o2 * 0.25f + b4.z;                           \
            float r3 = o3 * 0.25f + b4.w;                           \
            if (writeF32) {                                         \
                float4 w = {r0, r1, r2, r3};                        \
                *(float4*)(outF + (size_t)(node_)*64 + ci) = w;     \
            } else {                                                \
                ushort4 w;                                          \
                w.x = f2b(r0); w.y = f2b(r1);                       \
                w.z = f2b(r2); w.w = f2b(r3);                       \
                *(ushort4*)(outB + (size_t)(node_)*64 + ci) = w;    \
            }                                                       \
        }                                                           \
    }

    FINISH(base,     v0, degc0, xlA0, xlB0, xrA0, xrB0, l0,
           accA0, accB0, meaA0, meaB0);
    FINISH(base + 1, v1, degc1, xlA1, xlB1, xrA1, xrB1, l1,
           accA1, accB1, meaA1, meaB1);
#undef FINISH
#undef EDGE_MATH
}

// ---------- launch ----------
extern "C" void kernel_launch(void* const* d_in, const int* in_sizes, int n_in,
                              void* d_out, int out_size, void* d_ws, size_t ws_size,
                              hipStream_t stream) {
    const float* xf   = (const float*)d_in[0];
    const float* relf = (const float*)d_in[2];

    const int N = in_sizes[0] / 64;   // 20000
    const int E = in_sizes[3];        // 320000
    const int R = in_sizes[2] / 64;   // 512

    const float* Wl[2] = {(const float*)d_in[4],  (const float*)d_in[11]};
    const float* bl[2] = {(const float*)d_in[5],  (const float*)d_in[12]};
    const float* Wr[2] = {(const float*)d_in[6],  (const float*)d_in[13]};
    const float* br[2] = {(const float*)d_in[7],  (const float*)d_in[14]};
    const float* We[2] = {(const float*)d_in[8],  (const float*)d_in[15]};
    const float* at[2] = {(const float*)d_in[9],  (const float*)d_in[16]};
    const float* bb[2] = {(const float*)d_in[10], (const float*)d_in[17]};

    // workspace carve
    char* p = (char*)d_ws;
    auto alloc = [&](size_t bytes) -> void* {
        void* r = (void*)p;
        p += (bytes + 255) & ~(size_t)255;
        return r;
    };
    int* flags   = (int*)alloc(256);
    u16* rel16   = (u16*)alloc((size_t)R * 64 * 2);
    u16* w16[6];
    for (int i = 0; i < 6; i++) w16[i] = (u16*)alloc((size_t)256 * 64 * 2);
    int* cnt     = (int*)alloc((size_t)N * 4);
    int2* col    = (int2*)alloc((size_t)N * MAXDEG * 8);
    u8* xlb  = (u8*)alloc((size_t)N * 256);
    u8* xrb  = (u8*)alloc((size_t)N * 256);
    u8* reb0 = (u8*)alloc((size_t)R * 256);
    u8* reb1 = (u8*)alloc((size_t)R * 256);
    u16* h0  = (u16*)alloc((size_t)N * 64 * 2);

    float* out = (float*)d_out;

    // 1. prep: small conversions (+copyR), zero cnt, detect index storage
    CJobs jobs;
    jobs.j[0] = {relf,  rel16,  R * 16,   0};
    jobs.j[1] = {Wl[0], w16[0], 256 * 16, 0};
    jobs.j[2] = {Wr[0], w16[1], 256 * 16, 0};
    jobs.j[3] = {We[0], w16[2], 256 * 16, 0};
    jobs.j[4] = {Wl[1], w16[3], 256 * 16, 0};
    jobs.j[5] = {Wr[1], w16[4], 256 * 16, 0};
    jobs.j[6] = {We[1], w16[5], 256 * 16, 0};
    jobs.j[7] = {relf,  out + (size_t)N * 64, R * 16, 1};
    dim3 pgrid((N + 255) / 256, 9);
    prep_k<<<pgrid, 256, 0, stream>>>(jobs, (const u32*)d_in[1], flags, cnt, N);

    // 2. edge bucket-build || layer-0 GEMM (+ re tables for both layers)
    const int nbBuild = (E + 255) / 256;
    const int tilesN = (N + 63) / 64;
    build_gemm_k<<<nbBuild + tilesN + 16, 256, 0, stream>>>(
        d_in[1], d_in[3], flags, cnt, col, xf, rel16,
        w16[0], bl[0], w16[1], br[0], w16[2], w16[5],
        xlb, xrb, reb0, reb1, N, E, R, nbBuild, tilesN);

    // 3. layer-0 edge phase -> h0 (bf16); 2 nodes per wave, 8 per block
    edge_agg<<<(N + 7) / 8, 256, 0, stream>>>(cnt, col, xlb, xrb, reb0,
                                              at[0], bb[0], h0, out, 0, N);

    // 4. layer-1 GEMM (N rows): h0 @ {Wl1,Wr1}
    gemm_n_k<<<tilesN, 256, 0, stream>>>(h0, w16[3], bl[1], w16[4], br[1],
                                         xlb, xrb, N);

    // 5. layer-1 edge phase -> out (f32)
    edge_agg<<<(N + 7) / 8, 256, 0, stream>>>(cnt, col, xlb, xrb, reb1,
                                              at[1], bb[1], h0, out, 1, N);
}

// Round 19
// 199.770 us; speedup vs baseline: 1.0831x; 1.0603x over previous
//
#include <hip/hip_runtime.h>
#include <hip/hip_bf16.h>

typedef unsigned char u8;
typedef unsigned short u16;
typedef unsigned int u32;
typedef long long i64;
typedef __attribute__((ext_vector_type(8))) short bf16x8;
typedef __attribute__((ext_vector_type(4))) float f32x4;
typedef __attribute__((ext_vector_type(2))) float f32x2;

#define MAXDEG 64

// ---------- bf16 / fp8 helpers ----------
__device__ __forceinline__ u16 f2b(float f) {
    u32 u = __float_as_uint(f);
    u32 r = u + 0x7fffu + ((u >> 16) & 1u);   // round-to-nearest-even
    return (u16)(r >> 16);
}
// 4 consecutive fp8 (one u32) -> two f32x2 (HW cvt, stays packed)
__device__ __forceinline__ void load4f8v(const u8* p, f32x2& a, f32x2& b) {
    u32 q = *(const u32*)p;
    a = __builtin_amdgcn_cvt_pk_f32_fp8((int)q, false);
    b = __builtin_amdgcn_cvt_pk_f32_fp8((int)q, true);
}
__device__ __forceinline__ f32x2 vmax2(f32x2 a, f32x2 b) {
    return __builtin_elementwise_max(a, b);
}
// 8 f32 -> bf16x8 (for MFMA operand from f32 source)
__device__ __forceinline__ bf16x8 cvt8bf(const float* p) {
    float b[8];
    *(float4*)b = *(const float4*)(p);
    *(float4*)(b + 4) = *(const float4*)(p + 4);
    bf16x8 r;
#pragma unroll
    for (int j = 0; j < 8; j++) r[j] = (short)f2b(b[j]);
    return r;
}

// ---------- DPP 16-lane all-reduce-sum (VALU pipe, no LDS swizzle) ----------
// xor1 = quad_perm[1,0,3,2] (0xB1), xor2 = quad_perm[2,3,0,1] (0x4E).
// Steps 3/4 use row_half_mirror (0x141) / row_mirror (0x140): after xor1+xor2
// all lanes of a quad (resp. half-row) are equal, so the mirrored partner has
// the identical VALUE as the xor4/xor8 partner -> bit-identical sums.
template <int CTRL>
__device__ __forceinline__ float dpp_add(float x) {
    int y = __builtin_amdgcn_mov_dpp(__float_as_int(x), CTRL, 0xF, 0xF, true);
    return x + __int_as_float(y);
}
__device__ __forceinline__ float red16(float t) {
    t = dpp_add<0xB1>(t);    // + xor1
    t = dpp_add<0x4E>(t);    // + xor2
    t = dpp_add<0x141>(t);   // + cross-quad (row_half_mirror)
    t = dpp_add<0x140>(t);   // + cross-8 (row_mirror)
    return t;
}

// ---------- transposed-output GEMM, ONE channel-quarter per wave ----------
// r17 occupancy fix: old scheme = 1 wave does all 256 channels (16 subiters)
// -> only 1250 waves total = 1.2/SIMD, zero latency hiding. New: block = 16
// rows; wave w computes channel-quarter cth=w (4 ctl subiters, 64 channels)
// -> 4x blocks, ~4.9 waves/SIMD. Identical MFMA/bias/rounding per output.
// lane (m,quad): rows row0+m, channels cth*64+quad*16+ctl*4+{0..3}.
__device__ __forceinline__ void gemm_tile_q(
    bf16x8 a0, bf16x8 a1, const u16* __restrict__ W,
    const float* __restrict__ bias, u8* rowOut /* table + row*256 */,
    int m, int quad, int cth) {
    int nload = ((m >> 2) << 4) + (m & 3);   // + cth*64 + ctl*4
    int cbase = quad << 4;
    u32 pk[4];
#pragma unroll
    for (int ctl = 0; ctl < 4; ctl++) {
        int nl = cth * 64 + ctl * 4 + nload;
        bf16x8 w0 = *(const bf16x8*)(W + (size_t)nl * 64 + quad * 8);
        bf16x8 w1 = *(const bf16x8*)(W + (size_t)nl * 64 + 32 + quad * 8);
        f32x4 acc;
        if (bias) {
            float4 b4 = *(const float4*)(bias + cth * 64 + cbase + ctl * 4);
            acc[0] = b4.x; acc[1] = b4.y; acc[2] = b4.z; acc[3] = b4.w;
        } else {
            acc[0] = 0.f; acc[1] = 0.f; acc[2] = 0.f; acc[3] = 0.f;
        }
        acc = __builtin_amdgcn_mfma_f32_16x16x32_bf16(w0, a0, acc, 0, 0, 0);
        acc = __builtin_amdgcn_mfma_f32_16x16x32_bf16(w1, a1, acc, 0, 0, 0);
        u32 p = (u32)__builtin_amdgcn_cvt_pk_fp8_f32(acc[0], acc[1], 0, false);
        p = (u32)__builtin_amdgcn_cvt_pk_fp8_f32(acc[2], acc[3], (int)p, true);
        pk[ctl] = p;
    }
    uint4 v; v.x = pk[0]; v.y = pk[1]; v.z = pk[2]; v.w = pk[3];
    *(uint4*)(rowOut + cth * 64 + cbase) = v;
}

// ---------- prep: small conversions + copyR + zero cnt + detect ----------
struct CJob { const float* in; void* out; int n4; int mode; };  // 0: ->bf16, 1: f32 copy
struct CJobs { CJob j[8]; };
__global__ __launch_bounds__(256) void prep_k(CJobs jobs, const u32* __restrict__ ei,
                                              int* __restrict__ flags,
                                              int* __restrict__ cnt, int N) {
    int y = blockIdx.y;
    int i = blockIdx.x * 256 + threadIdx.x;
    if (y < 8) {
        CJob job = jobs.j[y];
        if (i < job.n4) {
            float4 v = ((const float4*)job.in)[i];
            if (job.mode == 0) {
                ushort4 w;
                w.x = f2b(v.x); w.y = f2b(v.y); w.z = f2b(v.z); w.w = f2b(v.w);
                ((ushort4*)job.out)[i] = w;
            } else {
                ((float4*)job.out)[i] = v;
            }
        }
    } else {
        if (i < N) cnt[i] = 0;
        if (blockIdx.x == 0 && threadIdx.x < 64) {
            int lane = threadIdx.x;
            int oddZero = 0;
            for (int k = lane; k < 128; k += 64)
                if (ei[2 * k + 1] == 0) oddZero++;
#pragma unroll
            for (int o = 32; o > 0; o >>= 1) oddZero += __shfl_xor(oddZero, o, 64);
            if (lane == 0) flags[0] = (oddZero >= 126) ? 1 : 0;
        }
    }
}

// ---------- fused: edge bucket-build || layer-0 GEMM (+ both re tables) ----
// GEMM blocks: 16 rows each, 4 waves = 4 channel-quarters (occupancy fix).
__global__ __launch_bounds__(256) void build_gemm_k(
    const void* __restrict__ ein, const void* __restrict__ rin,
    const int* __restrict__ flags, int* __restrict__ cnt,
    int2* __restrict__ col,
    const float* __restrict__ xf, const u16* __restrict__ rel16,
    const u16* __restrict__ Wl0, const float* __restrict__ bl0,
    const u16* __restrict__ Wr0, const float* __restrict__ br0,
    const u16* __restrict__ We0, const u16* __restrict__ We1,
    u8* __restrict__ xlb, u8* __restrict__ xrb,
    u8* __restrict__ reb0, u8* __restrict__ reb1,
    int N, int E, int R, int nbBuild, int tilesN16) {
    int b = blockIdx.x;
    if (b < nbBuild) {
        int i = b * 256 + threadIdx.x;
        if (i < E) {
            int f = flags[0];
            int s, d, r;
            if (f) {
                s = (int)((const i64*)ein)[i];
                d = (int)((const i64*)ein)[E + i];
                r = (int)((const i64*)rin)[i];
            } else {
                s = ((const int*)ein)[i];
                d = ((const int*)ein)[E + i];
                r = ((const int*)rin)[i];
            }
            s = max(0, min(s, N - 1));
            d = max(0, min(d, N - 1));
            r = max(0, min(r, R - 1));
            int slot = atomicAdd(&cnt[d], 1);
            if (slot < MAXDEG)
                col[(d << 6) + slot] = make_int2(s << 8, r << 8);  // pre-scaled
        }
        return;
    }
    int g = b - nbBuild;
    int wave = threadIdx.x >> 6, lane = threadIdx.x & 63;
    int m = lane & 15, quad = lane >> 4;

    if (g < tilesN16) {
        int row0 = g * 16;
        size_t row = (size_t)row0 + m;
        bf16x8 a0 = cvt8bf(xf + row * 64 + quad * 8);
        bf16x8 a1 = cvt8bf(xf + row * 64 + 32 + quad * 8);
        u8* rowA = xlb + row * 256;
        u8* rowB = xrb + row * 256;
        gemm_tile_q(a0, a1, Wl0, bl0, rowA, m, quad, wave);
        gemm_tile_q(a0, a1, Wr0, br0, rowB, m, quad, wave);
    } else {
        int g2 = g - tilesN16;            // 0..63: R tables, 16 rows each
        int layer = g2 >> 5;              // 32 blocks per layer (R=512)
        int row0 = (g2 & 31) * 16;
        size_t row = (size_t)row0 + m;
        bf16x8 a0 = *(const bf16x8*)(rel16 + row * 64 + quad * 8);
        bf16x8 a1 = *(const bf16x8*)(rel16 + row * 64 + 32 + quad * 8);
        const u16* WA = layer ? We1 : We0;
        u8* outA = layer ? reb1 : reb0;
        gemm_tile_q(a0, a1, WA, nullptr, outA + row * 256, m, quad, wave);
    }
}

// ---------- layer-1 GEMM: 16 rows/block, wave = channel-quarter ----------
__global__ __launch_bounds__(256) void gemm_n_k(
    const u16* __restrict__ Xin,
    const u16* __restrict__ Wl16, const float* __restrict__ bl,
    const u16* __restrict__ Wr16, const float* __restrict__ br,
    u8* __restrict__ xl, u8* __restrict__ xr, int N) {
    int wave = threadIdx.x >> 6, lane = threadIdx.x & 63;
    int row0 = blockIdx.x * 16;
    if (row0 >= N) return;
    int m = lane & 15, quad = lane >> 4;
    size_t row = (size_t)row0 + m;
    bf16x8 a0 = *(const bf16x8*)(Xin + row * 64 + quad * 8);
    bf16x8 a1 = *(const bf16x8*)(Xin + row * 64 + 32 + quad * 8);

    gemm_tile_q(a0, a1, Wl16, bl, xl + row * 256, m, quad, wave);
    gemm_tile_q(a0, a1, Wr16, br, xr + row * 256, m, quad, wave);
}

// ---------- fused edge phase: wave per node (r6 structure, 207.6us best) ---
// lane: head h = lane>>4, channels ci..ci+3, ci = (lane&15)*4. Fixed-ref
// softmax, packed f32 math, DPP alpha-reduce. Scheduling restructures all
// failed (r7/r9 ping-pong neutral, r12 split-K -4%, r17 2-node ILP -2%):
// this decomposition is at its issue/latency floor — keep it simple.
__global__ __launch_bounds__(256) void edge_agg(
    const int* __restrict__ cnt, const int2* __restrict__ col,
    const u8* __restrict__ xl, const u8* __restrict__ xr,
    const u8* __restrict__ re,
    const float* __restrict__ att, const float* __restrict__ bias,
    u16* __restrict__ outB, float* __restrict__ outF, int writeF32, int N) {
    int node = blockIdx.x * 4 + (threadIdx.x >> 6);
    node = __builtin_amdgcn_readfirstlane(node);   // provably wave-uniform
    int lane = threadIdx.x & 63;
    if (node >= N) return;
    int h = lane >> 4;
    int ci = (lane & 15) * 4;
    u32 hoff = (u32)(h * 64 + ci);
    const u8* xlh = xl + hoff;     // per-lane table bases (col idx pre-scaled)
    const u8* xrh = xr + hoff;
    const u8* reh = re + hoff;

    f32x2 avA, avB;
    {
        float4 a4 = *(const float4*)(att + hoff);
        avA[0] = a4.x; avA[1] = a4.y; avB[0] = a4.z; avB[1] = a4.w;
    }
    f32x2 xlA, xlB, xrA, xrB;
    load4f8v(xlh + ((u32)node << 8), xlA, xlB);
    load4f8v(xrh + ((u32)node << 8), xrA, xrB);

    int degc = cnt[node];
    degc = __builtin_amdgcn_readfirstlane(degc);   // uniform loop bound
    int deg = min(degc, MAXDEG);
    const int2* cb = col + ((u32)node << 6);

    float l = 0.f;
    f32x2 accA = {0.f, 0.f}, accB = {0.f, 0.f};
    f32x2 meaA = {0.f, 0.f}, meaB = {0.f, 0.f};
    int e = 0;

#define EDGE_MATH(xA, xB, vA, vB, tout)                \
    {                                                  \
        f32x2 mA = (xA + xrA) + vA;                    \
        f32x2 mB = (xB + xrB) + vB;                    \
        mA = vmax2(mA, mA * 0.2f);                     \
        mB = vmax2(mB, mB * 0.2f);                     \
        f32x2 tt = avA * mA + avB * mB;                \
        meaA += vA; meaB += vB;                        \
        tout = tt[0] + tt[1];                          \
    }

    for (; e + 3 < deg; e += 4) {
        int2 c0 = cb[e], c1 = cb[e + 1], c2 = cb[e + 2], c3 = cb[e + 3];
        f32x2 x0A, x0B, x1A, x1B, x2A, x2B, x3A, x3B;
        f32x2 v0A, v0B, v1A, v1B, v2A, v2B, v3A, v3B;
        load4f8v(xlh + (u32)c0.x, x0A, x0B);
        load4f8v(xlh + (u32)c1.x, x1A, x1B);
        load4f8v(xlh + (u32)c2.x, x2A, x2B);
        load4f8v(xlh + (u32)c3.x, x3A, x3B);
        load4f8v(reh + (u32)c0.y, v0A, v0B);
        load4f8v(reh + (u32)c1.y, v1A, v1B);
        load4f8v(reh + (u32)c2.y, v2A, v2B);
        load4f8v(reh + (u32)c3.y, v3A, v3B);
        float t0, t1, t2, t3;
        EDGE_MATH(x0A, x0B, v0A, v0B, t0);
        EDGE_MATH(x1A, x1B, v1A, v1B, t1);
        EDGE_MATH(x2A, x2B, v2A, v2B, t2);
        EDGE_MATH(x3A, x3B, v3A, v3B, t3);
        t0 = red16(t0);
        t1 = red16(t1);
        t2 = red16(t2);
        t3 = red16(t3);
        float p0 = __expf(t0), p1 = __expf(t1);
        float p2 = __expf(t2), p3 = __expf(t3);
        l += (p0 + p1) + (p2 + p3);
        accA += (x0A * p0 + x1A * p1) + (x2A * p2 + x3A * p3);
        accB += (x0B * p0 + x1B * p1) + (x2B * p2 + x3B * p3);
    }
    for (; e < deg; ++e) {
        int2 c0 = cb[e];
        f32x2 x0A, x0B, v0A, v0B;
        load4f8v(xlh + (u32)c0.x, x0A, x0B);
        load4f8v(reh + (u32)c0.y, v0A, v0B);
        float t0;
        EDGE_MATH(x0A, x0B, v0A, v0B, t0);
        t0 = red16(t0);
        float p0 = __expf(t0);
        l += p0;
        accA += x0A * p0;
        accB += x0B * p0;
    }
#undef EDGE_MATH

    // self-loop LAST: m = xl[n] + xr[n] + mean(incoming re rows)
    {
        float inv_d = 1.0f / fmaxf((float)degc, 1.0f);
        f32x2 mA = (xlA + xrA) + meaA * inv_d;
        f32x2 mB = (xlB + xrB) + meaB * inv_d;
        mA = vmax2(mA, mA * 0.2f);
        mB = vmax2(mB, mB * 0.2f);
        f32x2 tt = avA * mA + avB * mB;
        float ts = tt[0] + tt[1];
        ts = red16(ts);
        float ps = __expf(ts);
        l += ps;
        accA += xlA * ps;
        accB += xlB * ps;
    }

    float invl = 1.0f / l;
    float o0 = accA[0] * invl, o1 = accA[1] * invl;
    float o2 = accB[0] * invl, o3 = accB[1] * invl;
    // sum across the 4 head groups (lanes differing in bits 4,5)
    o0 += __shfl_xor(o0, 16, 64); o0 += __shfl_xor(o0, 32, 64);
    o1 += __shfl_xor(o1, 16, 64); o1 += __shfl_xor(o1, 32, 64);
    o2 += __shfl_xor(o2, 16, 64); o2 += __shfl_xor(o2, 32, 64);
    o3 += __shfl_xor(o3, 16, 64); o3 += __shfl_xor(o3, 32, 64);
    if (lane < 16) {
        float4 b4 = *(const float4*)(bias + ci);
        float r0 = o0 * 0.25f + b4.x;
        float r1 = o1 * 0.25f + b4.y;
        float r2 = o2 * 0.25f + b4.z;
        float r3 = o3 * 0.25f + b4.w;
        if (writeF32) {
            float4 w = {r0, r1, r2, r3};
            *(float4*)(outF + (size_t)node * 64 + ci) = w;
        } else {
            ushort4 w;
            w.x = f2b(r0); w.y = f2b(r1); w.z = f2b(r2); w.w = f2b(r3);
            *(ushort4*)(outB + (size_t)node * 64 + ci) = w;
        }
    }
}

// ---------- launch ----------
extern "C" void kernel_launch(void* const* d_in, const int* in_sizes, int n_in,
                              void* d_out, int out_size, void* d_ws, size_t ws_size,
                              hipStream_t stream) {
    const float* xf   = (const float*)d_in[0];
    const float* relf = (const float*)d_in[2];

    const int N = in_sizes[0] / 64;   // 20000
    const int E = in_sizes[3];        // 320000
    const int R = in_sizes[2] / 64;   // 512

    const float* Wl[2] = {(const float*)d_in[4],  (const float*)d_in[11]};
    const float* bl[2] = {(const float*)d_in[5],  (const float*)d_in[12]};
    const float* Wr[2] = {(const float*)d_in[6],  (const float*)d_in[13]};
    const float* br[2] = {(const float*)d_in[7],  (const float*)d_in[14]};
    const float* We[2] = {(const float*)d_in[8],  (const float*)d_in[15]};
    const float* at[2] = {(const float*)d_in[9],  (const float*)d_in[16]};
    const float* bb[2] = {(const float*)d_in[10], (const float*)d_in[17]};

    // workspace carve
    char* p = (char*)d_ws;
    auto alloc = [&](size_t bytes) -> void* {
        void* r = (void*)p;
        p += (bytes + 255) & ~(size_t)255;
        return r;
    };
    int* flags   = (int*)alloc(256);
    u16* rel16   = (u16*)alloc((size_t)R * 64 * 2);
    u16* w16[6];
    for (int i = 0; i < 6; i++) w16[i] = (u16*)alloc((size_t)256 * 64 * 2);
    int* cnt     = (int*)alloc((size_t)N * 4);
    int2* col    = (int2*)alloc((size_t)N * MAXDEG * 8);
    u8* xlb  = (u8*)alloc((size_t)N * 256);
    u8* xrb  = (u8*)alloc((size_t)N * 256);
    u8* reb0 = (u8*)alloc((size_t)R * 256);
    u8* reb1 = (u8*)alloc((size_t)R * 256);
    u16* h0  = (u16*)alloc((size_t)N * 64 * 2);

    float* out = (float*)d_out;

    // 1. prep: small conversions (+copyR), zero cnt, detect index storage
    CJobs jobs;
    jobs.j[0] = {relf,  rel16,  R * 16,   0};
    jobs.j[1] = {Wl[0], w16[0], 256 * 16, 0};
    jobs.j[2] = {Wr[0], w16[1], 256 * 16, 0};
    jobs.j[3] = {We[0], w16[2], 256 * 16, 0};
    jobs.j[4] = {Wl[1], w16[3], 256 * 16, 0};
    jobs.j[5] = {Wr[1], w16[4], 256 * 16, 0};
    jobs.j[6] = {We[1], w16[5], 256 * 16, 0};
    jobs.j[7] = {relf,  out + (size_t)N * 64, R * 16, 1};
    dim3 pgrid((N + 255) / 256, 9);
    prep_k<<<pgrid, 256, 0, stream>>>(jobs, (const u32*)d_in[1], flags, cnt, N);

    // 2. edge bucket-build || layer-0 GEMM (16-row blocks) + re tables
    const int nbBuild = (E + 255) / 256;
    const int tilesN16 = (N + 15) / 16;           // 1250
    const int rBlocks = 2 * ((R + 15) / 16);      // 64
    build_gemm_k<<<nbBuild + tilesN16 + rBlocks, 256, 0, stream>>>(
        d_in[1], d_in[3], flags, cnt, col, xf, rel16,
        w16[0], bl[0], w16[1], br[0], w16[2], w16[5],
        xlb, xrb, reb0, reb1, N, E, R, nbBuild, tilesN16);

    // 3. layer-0 edge phase -> h0 (bf16)
    edge_agg<<<(N + 3) / 4, 256, 0, stream>>>(cnt, col, xlb, xrb, reb0,
                                              at[0], bb[0], h0, out, 0, N);

    // 4. layer-1 GEMM (16-row blocks): h0 @ {Wl1,Wr1}
    gemm_n_k<<<tilesN16, 256, 0, stream>>>(h0, w16[3], bl[1], w16[4], br[1],
                                           xlb, xrb, N);

    // 5. layer-1 edge phase -> out (f32)
    edge_agg<<<(N + 3) / 4, 256, 0, stream>>>(cnt, col, xlb, xrb, reb1,
                                              at[1], bb[1], h0, out, 1, N);
}